// Round 8
// baseline (217.875 us; speedup 1.0000x reference)
//
#include <hip/hip_runtime.h>
#include <hip/hip_bf16.h>

typedef __attribute__((ext_vector_type(8))) short short8;
typedef __attribute__((ext_vector_type(4))) float f32x4;
typedef __attribute__((ext_vector_type(4))) unsigned int u32x4;

#define CIN    256
#define HW     1024
#define NT     8192   // B*H*W*heads
#define HD     64     // head dim

static __device__ __forceinline__ short f2bf(float f) {
    union { float f; unsigned u; } v; v.f = f;
    unsigned r = v.u + 0x7fffu + ((v.u >> 16) & 1u);
    return (short)(r >> 16);
}
// pack 2 fp32 -> 1 u32 of 2 bf16 (lo = first arg), RNE in HW
static __device__ __forceinline__ unsigned cvtpk(float lo, float hi) {
    unsigned r;
    asm("v_cvt_pk_bf16_f32 %0, %1, %2" : "=v"(r) : "v"(lo), "v"(hi));
    return r;
}

// ---------------- kernel 0: transpose+cast x [2][256][1024] f32 -> xT [2][1024][256] bf16
__global__ __launch_bounds__(256) void xpose(
    const float* __restrict__ x, short* __restrict__ xT)
{
    __shared__ float Ts[64][66];
    const int pt = blockIdx.x;   // 16 pos tiles
    const int ct = blockIdx.y;   // 4 cin tiles
    const int b  = blockIdx.z;   // 2
    const int t  = threadIdx.x;
    {
        const int r = t >> 2, p0 = (t & 3) * 16;
        const float* src = x + ((size_t)(b*CIN + ct*64 + r))*HW + pt*64 + p0;
        #pragma unroll
        for (int e = 0; e < 16; e += 2)
            *(float2*)&Ts[r][p0 + e] = *(const float2*)(src + e);
    }
    __syncthreads();
    {
        const int p = t >> 2, c0 = (t & 3) * 16;
        unsigned wds[8];
        #pragma unroll
        for (int j = 0; j < 8; ++j)
            wds[j] = cvtpk(Ts[c0 + 2*j][p], Ts[c0 + 2*j + 1][p]);
        short* dst = xT + ((size_t)(b*HW + pt*64 + p))*CIN + ct*64 + c0;
        u32x4 v0 = {wds[0], wds[1], wds[2], wds[3]};
        u32x4 v1 = {wds[4], wds[5], wds[6], wds[7]};
        *(u32x4*)dst = v0;
        *(u32x4*)(dst + 8) = v1;
    }
}

// ---------------- kernel 1: QKV projections from xT (pure bf16 GEMM) ----------------
// Q pre-scaled by log2(e)/8 so softmax uses raw v_exp_f32 (2^x).
__global__ __launch_bounds__(256) void qkv_proj(
    const short* __restrict__ xT,
    const float* __restrict__ Wq, const float* __restrict__ bq,
    const float* __restrict__ Wk, const float* __restrict__ bk,
    const float* __restrict__ Wv, const float* __restrict__ bv,
    short* __restrict__ Qs, short* __restrict__ Ks, short* __restrict__ VT)
{
    const int ot  = blockIdx.x;        // 4 och tiles of 64
    const int pt  = blockIdx.y;        // 16 pos tiles of 64
    const int mat = blockIdx.z >> 1;   // 0=Q 1=K 2=V
    const int b   = blockIdx.z & 1;
    const int lane = threadIdx.x & 63;
    const int w = threadIdx.x >> 6;
    const int g = lane >> 4, c = lane & 15;

    const float* W    = (mat == 0) ? Wq : (mat == 1) ? Wk : Wv;
    const float* bias = (mat == 0) ? bq : (mat == 1) ? bk : bv;

    const int ocA = ot*64 + w*16 + c;
    const short* xb = xT + (size_t)(b*HW + pt*64)*CIN;

    f32x4 acc[4];
    #pragma unroll
    for (int f = 0; f < 4; ++f) acc[f] = (f32x4){0.f,0.f,0.f,0.f};

    #pragma unroll 2
    for (int c0 = 0; c0 < CIN; c0 += 32) {
        const float* wr = W + ocA*CIN + c0 + 8*g;
        const f32x4 w0 = *(const f32x4*)(wr);
        const f32x4 w1 = *(const f32x4*)(wr + 4);
        u32x4 au;
        au[0] = cvtpk(w0[0], w0[1]); au[1] = cvtpk(w0[2], w0[3]);
        au[2] = cvtpk(w1[0], w1[1]); au[3] = cvtpk(w1[2], w1[3]);
        const short8 a = *(short8*)&au;
        #pragma unroll
        for (int f = 0; f < 4; ++f) {
            const short8 bb = *(const short8*)(xb + (f*16 + c)*CIN + c0 + 8*g);
            acc[f] = __builtin_amdgcn_mfma_f32_16x16x32_bf16(a, bb, acc[f], 0, 0, 0);
        }
    }

    const float sc = (mat == 0) ? 0.18033688011112043f : 1.0f;  // log2(e)/8
    #pragma unroll
    for (int f = 0; f < 4; ++f) {
        const int pos = pt*64 + f*16 + c;
        const int nb = (b*HW + pos) << 2;
        #pragma unroll
        for (int r = 0; r < 4; ++r) {
            const int och = ot*64 + w*16 + 4*g + r;
            const float v = (acc[f][r] + bias[och]) * sc;
            const int row = nb + (och >> 6);        // + head
            const int col = och & 63;               // d within head
            const short h = f2bf(v);
            if (mat == 0)      Qs[row*HD + col] = h;
            else if (mat == 1) Ks[row*HD + col] = h;
            else               VT[col*NT + row] = h;   // V transposed [64][8192]
        }
    }
}

// ---------------- kernel 2: flash attention, key-split, LDS-free, COUNTED-WAIT pipeline --
// WG = 4 waves x 16 q-rows. Swapped QK^T (S^T = mfma(K,Q)); permlane k-redistribution
// (verified round 7). Issue order per body (the round-8 fix):
//   [VT_i issue] -> QK(K_i: issued last body, OLDER than VT_i -> vmcnt(8), VT_i in flight)
//   -> exp/cvtpk (covers VT_i) -> [K_{i+1} issue] -> permlane -> PV(VT_i: vmcnt(8),
//   K_{i+1} rides across the body boundary). No drain anywhere in the loop.
#define ATTN_BODY(KC, KN, KS, KSN)                                              \
  {                                                                             \
    short8 vt[2][4];                                                            \
    _Pragma("unroll")                                                           \
    for (int t = 0; t < 2; ++t)                                                 \
      _Pragma("unroll")                                                         \
      for (int fd = 0; fd < 4; ++fd)                                            \
        vt[t][fd] = *(const short8*)(VT + (size_t)(fd*16 + c)*NT + (KS) + t*32 + 8*g); \
    unsigned pw[4][2];                                                          \
    _Pragma("unroll")                                                           \
    for (int f = 0; f < 4; ++f) {                                               \
      f32x4 z = (f32x4){0.f,0.f,0.f,0.f};                                       \
      z = __builtin_amdgcn_mfma_f32_16x16x32_bf16(KC[2*f],   aq0, z, 0, 0, 0);  \
      z = __builtin_amdgcn_mfma_f32_16x16x32_bf16(KC[2*f+1], aq1, z, 0, 0, 0);  \
      const float e0 = __builtin_amdgcn_exp2f(z[0]);                            \
      const float e1 = __builtin_amdgcn_exp2f(z[1]);                            \
      const float e2 = __builtin_amdgcn_exp2f(z[2]);                            \
      const float e3 = __builtin_amdgcn_exp2f(z[3]);                            \
      lsum += (e0 + e1) + (e2 + e3);                                            \
      pw[f][0] = cvtpk(e0, e1);                                                 \
      pw[f][1] = cvtpk(e2, e3);                                                 \
    }                                                                           \
    {                                                                           \
      const short* KnB = Ks + (size_t)(KSN)*HD;                                 \
      _Pragma("unroll")                                                         \
      for (int f = 0; f < 4; ++f) {                                             \
        KN[2*f]   = *(const short8*)(KnB + (f*16 + c)*HD + 8*g);                \
        KN[2*f+1] = *(const short8*)(KnB + (f*16 + c)*HD + 32 + 8*g);           \
      }                                                                         \
    }                                                                           \
    _Pragma("unroll")                                                           \
    for (int t = 0; t < 2; ++t) {                                               \
      unsigned a0 = pw[2*t][0], b0 = pw[2*t+1][0];                              \
      unsigned a1 = pw[2*t][1], b1 = pw[2*t+1][1];                              \
      asm("v_permlane32_swap_b32 %0, %1" : "+v"(a0), "+v"(b0));                 \
      asm("v_permlane32_swap_b32 %0, %1" : "+v"(a1), "+v"(b1));                 \
      asm("v_permlane16_swap_b32 %0, %1" : "+v"(a0), "+v"(b0));                 \
      asm("v_permlane16_swap_b32 %0, %1" : "+v"(a1), "+v"(b1));                 \
      u32x4 au; au[0] = a0; au[1] = a1; au[2] = b0; au[3] = b1;                 \
      const short8 ap = *(short8*)&au;                                          \
      _Pragma("unroll")                                                         \
      for (int fd = 0; fd < 4; ++fd)                                            \
        accO[fd] = __builtin_amdgcn_mfma_f32_16x16x32_bf16(ap, vt[t][fd], accO[fd], 0, 0, 0); \
    }                                                                           \
  }

__global__ __launch_bounds__(256, 3) void attn(
    const short* __restrict__ Qs, const short* __restrict__ Ks,
    const short* __restrict__ VT,
    float* __restrict__ Op, float* __restrict__ Ls, int kps)
{
    const int qb = blockIdx.x;           // 128 q-blocks
    const int sp = blockIdx.y;           // key split
    const int lane = threadIdx.x & 63;
    const int w = threadIdx.x >> 6;
    const int g = lane >> 4, c = lane & 15;

    const int qrow = qb*64 + w*16 + c;
    const short8 aq0 = *(const short8*)(Qs + qrow*HD + 8*g);
    const short8 aq1 = *(const short8*)(Qs + qrow*HD + 32 + 8*g);

    f32x4 accO[4];
    #pragma unroll
    for (int i = 0; i < 4; ++i) accO[i] = (f32x4){0.f,0.f,0.f,0.f};
    float lsum = 0.f;

    const int k0 = sp * kps;

    // prologue: issue K tile 0
    short8 kA[8], kB[8];
    #pragma unroll
    for (int f = 0; f < 4; ++f) {
        kA[2*f]   = *(const short8*)(Ks + (size_t)(k0 + f*16 + c)*HD + 8*g);
        kA[2*f+1] = *(const short8*)(Ks + (size_t)(k0 + f*16 + c)*HD + 32 + 8*g);
    }

    #pragma unroll 1
    for (int kb = 0; kb < kps; kb += 128) {
        const int ks = k0 + kb;
        ATTN_BODY(kA, kB, ks,      ks + 64)
        ATTN_BODY(kB, kA, ks + 64, ks + 128)
        // final prefetch overshoots into VT region: in-bounds, unused
    }

    // ---- write unnormalized partial O: lane reg r = O[q=w*16+4g+r][d=fd*16+c] ----
    #pragma unroll
    for (int fd = 0; fd < 4; ++fd)
        #pragma unroll
        for (int r = 0; r < 4; ++r) {
            const int qg = qb*64 + w*16 + 4*g + r;
            Op[(size_t)(sp*NT + qg)*HD + fd*16 + c] = accO[fd][r];
        }
    // ---- row-sum: lane (g,c) holds partial for q=c; reduce over the 4 g-groups ----
    lsum += __shfl_xor(lsum, 16);
    lsum += __shfl_xor(lsum, 32);
    if (g == 0)
        Ls[sp*NT + qb*64 + w*16 + c] = lsum;
}

// ---------------- kernel 3: merge key splits ----------------
__global__ __launch_bounds__(256) void combine(
    const float* __restrict__ Op, const float* __restrict__ Ls,
    short* __restrict__ Obf, int nsplit)
{
    const int idx = blockIdx.x*256 + threadIdx.x;
    const int qg = idx >> 6, d = idx & 63;
    float L = 0.f, o = 0.f;
    for (int s = 0; s < nsplit; ++s) {
        L += Ls[s*NT + qg];
        o += Op[(size_t)(s*NT + qg)*HD + d];
    }
    Obf[idx] = f2bf(o / L);
}

// ---------------- kernel 4: output projection ----------------
__global__ __launch_bounds__(256) void out_proj(
    const short* __restrict__ Obf,
    const float* __restrict__ Wo, const float* __restrict__ bo,
    float* __restrict__ out)
{
    const int ot = blockIdx.x;   // 4
    const int pt = blockIdx.y;   // 32 pos tiles of 32
    const int b  = blockIdx.z;   // 2
    const int lane = threadIdx.x & 63;
    const int w = threadIdx.x >> 6;
    const int g = lane >> 4, c = lane & 15;

    const int ocA = ot*64 + w*16 + c;
    f32x4 acc[2];
    #pragma unroll
    for (int f = 0; f < 2; ++f) acc[f] = (f32x4){0.f,0.f,0.f,0.f};

    #pragma unroll 2
    for (int c0 = 0; c0 < 256; c0 += 32) {
        const float* wr = Wo + ocA*256 + c0 + 8*g;
        const f32x4 w0 = *(const f32x4*)(wr);
        const f32x4 w1 = *(const f32x4*)(wr + 4);
        u32x4 au;
        au[0] = cvtpk(w0[0], w0[1]); au[1] = cvtpk(w0[2], w0[3]);
        au[2] = cvtpk(w1[0], w1[1]); au[3] = cvtpk(w1[2], w1[3]);
        const short8 a = *(short8*)&au;
        #pragma unroll
        for (int f = 0; f < 2; ++f) {
            const int pos = pt*32 + f*16 + c;
            const short8 bb = *(const short8*)(Obf + (size_t)(b*HW + pos)*256 + c0 + 8*g);
            acc[f] = __builtin_amdgcn_mfma_f32_16x16x32_bf16(a, bb, acc[f], 0, 0, 0);
        }
    }
    #pragma unroll
    for (int f = 0; f < 2; ++f) {
        const int pos = pt*32 + f*16 + c;
        #pragma unroll
        for (int r = 0; r < 4; ++r) {
            const int och = ot*64 + w*16 + 4*g + r;
            out[(size_t)(b*256 + och)*HW + pos] = acc[f][r] + bo[och];
        }
    }
}

extern "C" void kernel_launch(void* const* d_in, const int* in_sizes, int n_in,
                              void* d_out, int out_size, void* d_ws, size_t ws_size,
                              hipStream_t stream)
{
    (void)in_sizes; (void)n_in; (void)out_size;
    const float* x  = (const float*)d_in[0];
    const float* Wq = (const float*)d_in[1];
    const float* bq = (const float*)d_in[2];
    const float* Wk = (const float*)d_in[3];
    const float* bk = (const float*)d_in[4];
    const float* Wv = (const float*)d_in[5];
    const float* bv = (const float*)d_in[6];
    const float* Wo = (const float*)d_in[7];
    const float* bo = (const float*)d_in[8];
    float* out = (float*)d_out;
    char* ws = (char*)d_ws;

    const size_t need8 = (4u<<20) + 8*(size_t)NT*HD*4 + 8*(size_t)NT*4;
    const int nsplit = (ws_size >= need8) ? 8 : 4;
    const int kps = NT / nsplit;

    short* Qs  = (short*)(ws);                 // 1 MB  [8192][64] bf16, pre-scaled
    short* Ks  = (short*)(ws + (1u<<20));      // 1 MB  [8192][64] bf16
    short* VT  = (short*)(ws + (2u<<20));      // 1 MB  [64][8192] bf16 (transposed)
    short* Obf = (short*)(ws + (3u<<20));      // 1 MB  [8192][64] bf16  (also xT before combine)
    float* Op  = (float*)(ws + (4u<<20));      // nsplit*2MB [ns][8192][64] fp32
    float* Ls  = (float*)(ws + (4u<<20) + (size_t)nsplit*NT*HD*4);
    short* xT  = Obf;                          // alias: dead before combine writes Obf

    xpose<<<dim3(16, 4, 2), 256, 0, stream>>>(x, xT);
    qkv_proj<<<dim3(4, 16, 6), 256, 0, stream>>>(xT, Wq, bq, Wk, bk, Wv, bv, Qs, Ks, VT);
    attn<<<dim3(NT/64, nsplit), 256, 0, stream>>>(Qs, Ks, VT, Op, Ls, kps);
    combine<<<dim3((NT*HD)/256), 256, 0, stream>>>(Op, Ls, Obf, nsplit);
    out_proj<<<dim3(4, 32, 2), 256, 0, stream>>>(Obf, Wo, bo, out);
}

// Round 9
// 130.033 us; speedup vs baseline: 1.6755x; 1.6755x over previous
//
#include <hip/hip_runtime.h>
#include <hip/hip_bf16.h>

typedef __attribute__((ext_vector_type(8))) short short8;
typedef __attribute__((ext_vector_type(4))) float f32x4;
typedef __attribute__((ext_vector_type(4))) unsigned int u32x4;

#define CIN    256
#define HW     1024
#define NT     8192   // B*H*W*heads
#define HD     64     // head dim

static __device__ __forceinline__ short f2bf(float f) {
    union { float f; unsigned u; } v; v.f = f;
    unsigned r = v.u + 0x7fffu + ((v.u >> 16) & 1u);
    return (short)(r >> 16);
}
// pack 2 fp32 -> 1 u32 of 2 bf16 (lo = first arg), RNE in HW
static __device__ __forceinline__ unsigned cvtpk(float lo, float hi) {
    unsigned r;
    asm("v_cvt_pk_bf16_f32 %0, %1, %2" : "=v"(r) : "v"(lo), "v"(hi));
    return r;
}
// async global->LDS, 16B per lane; dest = wave-uniform base + lane*16
static __device__ __forceinline__ void gload16(const void* g, void* l) {
    __builtin_amdgcn_global_load_lds(
        (const __attribute__((address_space(1))) unsigned int*)g,
        (__attribute__((address_space(3))) unsigned int*)l, 16, 0, 0);
}

// ---------------- kernel 0: transpose+cast x [2][256][1024] f32 -> xT [2][1024][256] bf16
__global__ __launch_bounds__(256) void xpose(
    const float* __restrict__ x, short* __restrict__ xT)
{
    __shared__ float Ts[64][66];
    const int pt = blockIdx.x;   // 16 pos tiles
    const int ct = blockIdx.y;   // 4 cin tiles
    const int b  = blockIdx.z;   // 2
    const int t  = threadIdx.x;
    {
        const int r = t >> 2, p0 = (t & 3) * 16;
        const float* src = x + ((size_t)(b*CIN + ct*64 + r))*HW + pt*64 + p0;
        #pragma unroll
        for (int e = 0; e < 16; e += 2)
            *(float2*)&Ts[r][p0 + e] = *(const float2*)(src + e);
    }
    __syncthreads();
    {
        const int p = t >> 2, c0 = (t & 3) * 16;
        unsigned wds[8];
        #pragma unroll
        for (int j = 0; j < 8; ++j)
            wds[j] = cvtpk(Ts[c0 + 2*j][p], Ts[c0 + 2*j + 1][p]);
        short* dst = xT + ((size_t)(b*HW + pt*64 + p))*CIN + ct*64 + c0;
        u32x4 v0 = {wds[0], wds[1], wds[2], wds[3]};
        u32x4 v1 = {wds[4], wds[5], wds[6], wds[7]};
        *(u32x4*)dst = v0;
        *(u32x4*)(dst + 8) = v1;
    }
}

// ---------------- kernel 1: QKV projections from xT (pure bf16 GEMM) ----------------
// Q pre-scaled by log2(e)/8 so softmax uses raw v_exp_f32 (2^x).
__global__ __launch_bounds__(256) void qkv_proj(
    const short* __restrict__ xT,
    const float* __restrict__ Wq, const float* __restrict__ bq,
    const float* __restrict__ Wk, const float* __restrict__ bk,
    const float* __restrict__ Wv, const float* __restrict__ bv,
    short* __restrict__ Qs, short* __restrict__ Ks, short* __restrict__ VT)
{
    const int ot  = blockIdx.x;        // 4 och tiles of 64
    const int pt  = blockIdx.y;        // 16 pos tiles of 64
    const int mat = blockIdx.z >> 1;   // 0=Q 1=K 2=V
    const int b   = blockIdx.z & 1;
    const int lane = threadIdx.x & 63;
    const int w = threadIdx.x >> 6;
    const int g = lane >> 4, c = lane & 15;

    const float* W    = (mat == 0) ? Wq : (mat == 1) ? Wk : Wv;
    const float* bias = (mat == 0) ? bq : (mat == 1) ? bk : bv;

    const int ocA = ot*64 + w*16 + c;
    const short* xb = xT + (size_t)(b*HW + pt*64)*CIN;

    f32x4 acc[4];
    #pragma unroll
    for (int f = 0; f < 4; ++f) acc[f] = (f32x4){0.f,0.f,0.f,0.f};

    #pragma unroll 2
    for (int c0 = 0; c0 < CIN; c0 += 32) {
        const float* wr = W + ocA*CIN + c0 + 8*g;
        const f32x4 w0 = *(const f32x4*)(wr);
        const f32x4 w1 = *(const f32x4*)(wr + 4);
        u32x4 au;
        au[0] = cvtpk(w0[0], w0[1]); au[1] = cvtpk(w0[2], w0[3]);
        au[2] = cvtpk(w1[0], w1[1]); au[3] = cvtpk(w1[2], w1[3]);
        const short8 a = *(short8*)&au;
        #pragma unroll
        for (int f = 0; f < 4; ++f) {
            const short8 bb = *(const short8*)(xb + (f*16 + c)*CIN + c0 + 8*g);
            acc[f] = __builtin_amdgcn_mfma_f32_16x16x32_bf16(a, bb, acc[f], 0, 0, 0);
        }
    }

    const float sc = (mat == 0) ? 0.18033688011112043f : 1.0f;  // log2(e)/8
    #pragma unroll
    for (int f = 0; f < 4; ++f) {
        const int pos = pt*64 + f*16 + c;
        const int nb = (b*HW + pos) << 2;
        #pragma unroll
        for (int r = 0; r < 4; ++r) {
            const int och = ot*64 + w*16 + 4*g + r;
            const float v = (acc[f][r] + bias[och]) * sc;
            const int row = nb + (och >> 6);        // + head
            const int col = och & 63;               // d within head
            const short h = f2bf(v);
            if (mat == 0)      Qs[row*HD + col] = h;
            else if (mat == 1) Ks[row*HD + col] = h;
            else               VT[col*NT + row] = h;   // V transposed [64][8192]
        }
    }
}

// ---------------- kernel 2: flash attention, global_load_lds 2-phase pipeline ------------
// WG = 4 waves x 16 q-rows, 64-key tiles. K/V tiles staged direct-to-LDS (shared by all
// 4 waves; no VGPR round-trip -> regalloc can't serialize it). Double-buffered, raw
// s_barrier + counted vmcnt(4) (never 0 in loop). LDS tile layout: per quarter f (16 rows),
// row r holds its 8 16B-chunks PERMUTED: slot js contains chunk js^(r&7) (XOR swizzle
// applied on the GLOBAL source address; LDS dest linear = rule #21). ds_read at
// slot j^(r&7) -> bank-spread, b128 8-phase minimum. QK/exp/permlane/PV identical to the
// verified round-7 dataflow.
#define STAGE(BUF, KSN) {                                                         \
    char* kb = smem + (BUF)*16384 + w*2048;                                       \
    const short* gk = Ks + (size_t)((KSN) + w*16 + r8)*HD + js8;                  \
    const short* gv = VT + (size_t)(w*16 + r8)*NT + (KSN) + js8;                  \
    gload16(gk,          kb);                                                     \
    gload16(gk + 8*HD,   kb + 1024);                                              \
    gload16(gv,          kb + 8192);                                              \
    gload16(gv + 8*NT,   kb + 9216);                                              \
}

#define COMPUTE(BUF) {                                                            \
    const char* Kb = smem + (BUF)*16384;                                          \
    const char* Vb = Kb + 8192;                                                   \
    unsigned pw[4][2];                                                            \
    _Pragma("unroll")                                                             \
    for (int f = 0; f < 4; ++f) {                                                 \
      const short8 kc0 = *(const short8*)(Kb + f*2048 + c*128 + 16*(g ^ swr));    \
      const short8 kc1 = *(const short8*)(Kb + f*2048 + c*128 + 16*((g+4) ^ swr));\
      f32x4 z = (f32x4){0.f,0.f,0.f,0.f};                                         \
      z = __builtin_amdgcn_mfma_f32_16x16x32_bf16(kc0, aq0, z, 0, 0, 0);          \
      z = __builtin_amdgcn_mfma_f32_16x16x32_bf16(kc1, aq1, z, 0, 0, 0);          \
      const float e0 = __builtin_amdgcn_exp2f(z[0]);                              \
      const float e1 = __builtin_amdgcn_exp2f(z[1]);                              \
      const float e2 = __builtin_amdgcn_exp2f(z[2]);                              \
      const float e3 = __builtin_amdgcn_exp2f(z[3]);                              \
      lsum += (e0 + e1) + (e2 + e3);                                              \
      pw[f][0] = cvtpk(e0, e1);                                                   \
      pw[f][1] = cvtpk(e2, e3);                                                   \
    }                                                                             \
    _Pragma("unroll")                                                             \
    for (int t = 0; t < 2; ++t) {                                                 \
      unsigned a0 = pw[2*t][0], b0 = pw[2*t+1][0];                                \
      unsigned a1 = pw[2*t][1], b1 = pw[2*t+1][1];                                \
      asm("v_permlane32_swap_b32 %0, %1" : "+v"(a0), "+v"(b0));                   \
      asm("v_permlane32_swap_b32 %0, %1" : "+v"(a1), "+v"(b1));                   \
      asm("v_permlane16_swap_b32 %0, %1" : "+v"(a0), "+v"(b0));                   \
      asm("v_permlane16_swap_b32 %0, %1" : "+v"(a1), "+v"(b1));                   \
      u32x4 au; au[0] = a0; au[1] = a1; au[2] = b0; au[3] = b1;                   \
      const short8 ap = *(short8*)&au;                                            \
      _Pragma("unroll")                                                           \
      for (int fd = 0; fd < 4; ++fd) {                                            \
        const short8 vv = *(const short8*)(Vb + fd*2048 + c*128 + 16*((4*t+g) ^ swr)); \
        accO[fd] = __builtin_amdgcn_mfma_f32_16x16x32_bf16(ap, vv, accO[fd], 0, 0, 0); \
      }                                                                           \
    }                                                                             \
}

__global__ __launch_bounds__(256) void attn(
    const short* __restrict__ Qs, const short* __restrict__ Ks,
    const short* __restrict__ VT,
    float* __restrict__ Op, float* __restrict__ Ls, int kps)
{
    __shared__ char smem[32768];         // 2 buf x (K 8KB + V 8KB)
    const int qb = blockIdx.x;           // 128 q-blocks
    const int sp = blockIdx.y;           // key split
    const int lane = threadIdx.x & 63;
    const int w = threadIdx.x >> 6;
    const int g = lane >> 4, c = lane & 15;
    const int swr = c & 7;
    const int r8 = lane >> 3, j8 = lane & 7;
    const int js8 = 8 * (j8 ^ r8);       // pre-swizzled source chunk (elements)

    const int qrow = qb*64 + w*16 + c;
    const short8 aq0 = *(const short8*)(Qs + qrow*HD + 8*g);
    const short8 aq1 = *(const short8*)(Qs + qrow*HD + 32 + 8*g);
    asm volatile("s_waitcnt vmcnt(0)" ::: "memory");   // Q resident; stages are the only VMEM

    f32x4 accO[4];
    #pragma unroll
    for (int i = 0; i < 4; ++i) accO[i] = (f32x4){0.f,0.f,0.f,0.f};
    float lsum = 0.f;

    const int k0 = sp * kps;
    const int ntiles = kps >> 6;

    STAGE(0, k0)
    #pragma unroll 1
    for (int it = 0; it < ntiles - 1; ++it) {
        STAGE((it+1)&1, k0 + (it+1)*64)
        asm volatile("s_waitcnt vmcnt(4)" ::: "memory");  // my 4 oldest (cur tile) landed
        __builtin_amdgcn_s_barrier();                     // all waves' quarters landed
        COMPUTE(it&1)
        __builtin_amdgcn_s_barrier();                     // WAR: done reading before restage
    }
    asm volatile("s_waitcnt vmcnt(0)" ::: "memory");
    __builtin_amdgcn_s_barrier();
    COMPUTE((ntiles-1)&1)

    // ---- write unnormalized partial O: lane reg r = O[q=w*16+4g+r][d=fd*16+c] ----
    #pragma unroll
    for (int fd = 0; fd < 4; ++fd)
        #pragma unroll
        for (int r = 0; r < 4; ++r) {
            const int qg = qb*64 + w*16 + 4*g + r;
            Op[(size_t)(sp*NT + qg)*HD + fd*16 + c] = accO[fd][r];
        }
    // ---- row-sum: lane (g,c) holds partial for q=c; reduce over the 4 g-groups ----
    lsum += __shfl_xor(lsum, 16);
    lsum += __shfl_xor(lsum, 32);
    if (g == 0)
        Ls[sp*NT + qb*64 + w*16 + c] = lsum;
}

// ---------------- kernel 3: merge key splits ----------------
__global__ __launch_bounds__(256) void combine(
    const float* __restrict__ Op, const float* __restrict__ Ls,
    short* __restrict__ Obf, int nsplit)
{
    const int idx = blockIdx.x*256 + threadIdx.x;
    const int qg = idx >> 6, d = idx & 63;
    float L = 0.f, o = 0.f;
    for (int s = 0; s < nsplit; ++s) {
        L += Ls[s*NT + qg];
        o += Op[(size_t)(s*NT + qg)*HD + d];
    }
    Obf[idx] = f2bf(o / L);
}

// ---------------- kernel 4: output projection ----------------
__global__ __launch_bounds__(256) void out_proj(
    const short* __restrict__ Obf,
    const float* __restrict__ Wo, const float* __restrict__ bo,
    float* __restrict__ out)
{
    const int ot = blockIdx.x;   // 4
    const int pt = blockIdx.y;   // 32 pos tiles of 32
    const int b  = blockIdx.z;   // 2
    const int lane = threadIdx.x & 63;
    const int w = threadIdx.x >> 6;
    const int g = lane >> 4, c = lane & 15;

    const int ocA = ot*64 + w*16 + c;
    f32x4 acc[2];
    #pragma unroll
    for (int f = 0; f < 2; ++f) acc[f] = (f32x4){0.f,0.f,0.f,0.f};

    #pragma unroll 2
    for (int c0 = 0; c0 < 256; c0 += 32) {
        const float* wr = Wo + ocA*256 + c0 + 8*g;
        const f32x4 w0 = *(const f32x4*)(wr);
        const f32x4 w1 = *(const f32x4*)(wr + 4);
        u32x4 au;
        au[0] = cvtpk(w0[0], w0[1]); au[1] = cvtpk(w0[2], w0[3]);
        au[2] = cvtpk(w1[0], w1[1]); au[3] = cvtpk(w1[2], w1[3]);
        const short8 a = *(short8*)&au;
        #pragma unroll
        for (int f = 0; f < 2; ++f) {
            const int pos = pt*32 + f*16 + c;
            const short8 bb = *(const short8*)(Obf + (size_t)(b*HW + pos)*256 + c0 + 8*g);
            acc[f] = __builtin_amdgcn_mfma_f32_16x16x32_bf16(a, bb, acc[f], 0, 0, 0);
        }
    }
    #pragma unroll
    for (int f = 0; f < 2; ++f) {
        const int pos = pt*32 + f*16 + c;
        #pragma unroll
        for (int r = 0; r < 4; ++r) {
            const int och = ot*64 + w*16 + 4*g + r;
            out[(size_t)(b*256 + och)*HW + pos] = acc[f][r] + bo[och];
        }
    }
}

extern "C" void kernel_launch(void* const* d_in, const int* in_sizes, int n_in,
                              void* d_out, int out_size, void* d_ws, size_t ws_size,
                              hipStream_t stream)
{
    (void)in_sizes; (void)n_in; (void)out_size;
    const float* x  = (const float*)d_in[0];
    const float* Wq = (const float*)d_in[1];
    const float* bq = (const float*)d_in[2];
    const float* Wk = (const float*)d_in[3];
    const float* bk = (const float*)d_in[4];
    const float* Wv = (const float*)d_in[5];
    const float* bv = (const float*)d_in[6];
    const float* Wo = (const float*)d_in[7];
    const float* bo = (const float*)d_in[8];
    float* out = (float*)d_out;
    char* ws = (char*)d_ws;

    const size_t need8 = (4u<<20) + 8*(size_t)NT*HD*4 + 8*(size_t)NT*4;
    const int nsplit = (ws_size >= need8) ? 8 : 4;
    const int kps = NT / nsplit;

    short* Qs  = (short*)(ws);                 // 1 MB  [8192][64] bf16, pre-scaled
    short* Ks  = (short*)(ws + (1u<<20));      // 1 MB  [8192][64] bf16
    short* VT  = (short*)(ws + (2u<<20));      // 1 MB  [64][8192] bf16 (transposed)
    short* Obf = (short*)(ws + (3u<<20));      // 1 MB  [8192][64] bf16  (also xT before combine)
    float* Op  = (float*)(ws + (4u<<20));      // nsplit*2MB [ns][8192][64] fp32
    float* Ls  = (float*)(ws + (4u<<20) + (size_t)nsplit*NT*HD*4);
    short* xT  = Obf;                          // alias: dead before combine writes Obf

    xpose<<<dim3(16, 4, 2), 256, 0, stream>>>(x, xT);
    qkv_proj<<<dim3(4, 16, 6), 256, 0, stream>>>(xT, Wq, bq, Wk, bk, Wv, bv, Qs, Ks, VT);
    attn<<<dim3(NT/64, nsplit), 256, 0, stream>>>(Qs, Ks, VT, Op, Ls, kps);
    combine<<<dim3((NT*HD)/256), 256, 0, stream>>>(Op, Ls, Obf, nsplit);
    out_proj<<<dim3(4, 32, 2), 256, 0, stream>>>(Obf, Wo, bo, out);
}